// Round 1
// baseline (174.738 us; speedup 1.0000x reference)
//
#include <hip/hip_runtime.h>
#include <hip/hip_bf16.h>

// Problem constants
#define HH 24
#define WW 24
#define HW 576          // 24*24
#define CC 512
#define NHEAD 8
#define HDIM 64
#define PW 30           // padded width/height
#define PP 900          // 30*30 distinct padded positions

__device__ __forceinline__ int imin3(int a, int b, int c) {
    int m = a < b ? a : b;
    return m < c ? m : c;
}

#define FMA16(a, b, acc)                                   \
    acc[0][0] = fmaf(a.x, b.x, acc[0][0]);                 \
    acc[0][1] = fmaf(a.x, b.y, acc[0][1]);                 \
    acc[0][2] = fmaf(a.x, b.z, acc[0][2]);                 \
    acc[0][3] = fmaf(a.x, b.w, acc[0][3]);                 \
    acc[1][0] = fmaf(a.y, b.x, acc[1][0]);                 \
    acc[1][1] = fmaf(a.y, b.y, acc[1][1]);                 \
    acc[1][2] = fmaf(a.y, b.z, acc[1][2]);                 \
    acc[1][3] = fmaf(a.y, b.w, acc[1][3]);                 \
    acc[2][0] = fmaf(a.z, b.x, acc[2][0]);                 \
    acc[2][1] = fmaf(a.z, b.y, acc[2][1]);                 \
    acc[2][2] = fmaf(a.z, b.z, acc[2][2]);                 \
    acc[2][3] = fmaf(a.z, b.w, acc[2][3]);                 \
    acc[3][0] = fmaf(a.w, b.x, acc[3][0]);                 \
    acc[3][1] = fmaf(a.w, b.y, acc[3][1]);                 \
    acc[3][2] = fmaf(a.w, b.z, acc[3][2]);                 \
    acc[3][3] = fmaf(a.w, b.w, acc[3][3]);

// ---------------------------------------------------------------------------
// Kernel 1: fused Q/K/V 1x1-conv projections (fp32 GEMM, reflect-pad gather
// folded into the X staging).
//   sel 0: q = Wq*x + bq over 576 pixels     -> qT [head][pix][d]
//   sel 1: k = Wk*xp + bk over 900 positions -> kM [chan][900]
//   sel 2: v = Wv*xp + bv over 900 positions -> vT [head][pos][d]
// grid (15, 8, 3), block 256. 64x64 tile, 4x4 micro-tile.
// ---------------------------------------------------------------------------
__global__ __launch_bounds__(256) void qkv_proj(
    const float* __restrict__ x,
    const float* __restrict__ Wq, const float* __restrict__ bq,
    const float* __restrict__ Wk, const float* __restrict__ bk,
    const float* __restrict__ Wv, const float* __restrict__ bv,
    float* __restrict__ qT, float* __restrict__ kM, float* __restrict__ vT)
{
    const int sel = blockIdx.z;
    const int ncols = (sel == 0) ? HW : PP;
    const int col0 = blockIdx.x * 64;
    if (col0 >= ncols) return;                    // uniform per block
    const int row0 = blockIdx.y * 64;
    const float* W    = (sel == 0) ? Wq : (sel == 1) ? Wk : Wv;
    const float* bias = (sel == 0) ? bq : (sel == 1) ? bk : bv;

    __shared__ __align__(16) float Wl[16][68];    // W^T tile (pad 68: bank spread)
    __shared__ __align__(16) float Xl[16][64];    // X tile
    __shared__ int smap[64];                      // col -> source pixel (reflect pad)

    const int t = threadIdx.x;
    if (t < 64) {
        int pp = col0 + t;
        int src;
        if (sel == 0) {
            src = (pp < HW) ? pp : 0;
        } else {
            if (pp >= PP) pp = PP - 1;
            int y  = pp / PW, xw = pp - y * PW;
            int iy = y - 3;  iy = (iy < 0) ? -iy : (iy > 23 ? 46 - iy : iy);
            int ix = xw - 3; ix = (ix < 0) ? -ix : (ix > 23 ? 46 - ix : ix);
            src = iy * WW + ix;
        }
        smap[t] = src;
    }
    __syncthreads();

    const int ty = t >> 4, tx = t & 15;
    const int r0 = ty * 4, cl0 = tx * 4;
    const int wo = t >> 2, wc = (t & 3) * 4;      // W staging: 64 rows x 16 k
    const int xc = t >> 4, xj = (t & 15) * 4;     // X staging: 16 k x 64 cols

    float acc[4][4] = {};

    for (int k0 = 0; k0 < CC; k0 += 16) {
        // stage W^T: Wl[c][o]
        {
            const float4 w4 = *(const float4*)&W[(row0 + wo) * CC + k0 + wc];
            Wl[wc + 0][wo] = w4.x;
            Wl[wc + 1][wo] = w4.y;
            Wl[wc + 2][wo] = w4.z;
            Wl[wc + 3][wo] = w4.w;
        }
        // stage X: Xl[c][j] (gather through smap for padded k/v)
        {
            const float* xr = &x[(k0 + xc) * HW];
            if (sel == 0) {
                *(float4*)&Xl[xc][xj] = *(const float4*)&xr[col0 + xj];
            } else {
                Xl[xc][xj + 0] = xr[smap[xj + 0]];
                Xl[xc][xj + 1] = xr[smap[xj + 1]];
                Xl[xc][xj + 2] = xr[smap[xj + 2]];
                Xl[xc][xj + 3] = xr[smap[xj + 3]];
            }
        }
        __syncthreads();
        #pragma unroll
        for (int kk = 0; kk < 16; ++kk) {
            const float4 a = *(const float4*)&Wl[kk][r0];
            const float4 b = *(const float4*)&Xl[kk][cl0];
            FMA16(a, b, acc)
        }
        __syncthreads();
    }

    // epilogue: add bias, store
    if (sel == 1) {
        #pragma unroll
        for (int i = 0; i < 4; ++i) {
            const int o = row0 + r0 + i;
            const float bb = bias[o];
            const int cc = col0 + cl0;
            #pragma unroll
            for (int j = 0; j < 4; ++j)
                if (cc + j < PP) kM[o * PP + cc + j] = acc[i][j] + bb;
        }
    } else {
        float* T = (sel == 0) ? qT : vT;
        const int hd = blockIdx.y;                 // 64-row tile == one head
        const float b0 = bias[row0 + r0 + 0];
        const float b1 = bias[row0 + r0 + 1];
        const float b2 = bias[row0 + r0 + 2];
        const float b3 = bias[row0 + r0 + 3];
        #pragma unroll
        for (int j = 0; j < 4; ++j) {
            const int cc = col0 + cl0 + j;
            if (cc < ncols) {
                float4 o4 = make_float4(acc[0][j] + b0, acc[1][j] + b1,
                                        acc[2][j] + b2, acc[3][j] + b3);
                *(float4*)&T[(hd * ncols + cc) * HDIM + r0] = o4;
            }
        }
    }
}

// ---------------------------------------------------------------------------
// Kernel 2: fused attention with multiplicity-weighted softmax over the 900
// distinct padded key positions (exactly equivalent to the reference's
// softmax over 49*576 expanded keys).
// One block = (head, 16 queries). grid (36, 8), block 256. LDS ~62 KB.
// ---------------------------------------------------------------------------
__global__ __launch_bounds__(256) void attn(
    const float* __restrict__ qT, const float* __restrict__ kM,
    const float* __restrict__ vT, const float* __restrict__ x,
    const float* __restrict__ gamma, float* __restrict__ out)
{
    const int hd = blockIdx.y;
    const int q0 = blockIdx.x * 16;
    const int t = threadIdx.x;

    __shared__ __align__(16) float q_t[64][16];    // q transposed [d][qi]
    __shared__ __align__(16) float e_s[16 * 904];  // energies->weights [qi][p]
    __shared__ float red[16];                      // softmax denominators

    // stage q transposed (fully coalesced 4 KB read)
    {
        const int qi = t >> 4, d0 = (t & 15) * 4;
        const float4 qv = *(const float4*)&qT[(hd * HW + q0 + qi) * HDIM + d0];
        q_t[d0 + 0][qi] = qv.x;
        q_t[d0 + 1][qi] = qv.y;
        q_t[d0 + 2][qi] = qv.z;
        q_t[d0 + 3][qi] = qv.w;
    }
    __syncthreads();

    // ---- Phase 1: energies e[qi][p] = q . k  (k streamed from global/L2) ----
    const int pg = t & 63, qg = t >> 6;            // 64 col-groups x 4 query-groups
    const float* kbase = &kM[hd * HDIM * PP];
    for (int p0 = 0; p0 < PP; p0 += 256) {
        const int pl = p0 + pg * 4;
        if (pl < PP) {                             // pl%4==0, never straddles 900
            float acc[4][4] = {};
            #pragma unroll 8
            for (int d = 0; d < 64; ++d) {
                const float4 b = *(const float4*)&kbase[d * PP + pl]; // 1KB/wave, coalesced
                const float4 a = *(const float4*)&q_t[d][qg * 4];     // LDS broadcast
                FMA16(a, b, acc)
            }
            #pragma unroll
            for (int i = 0; i < 4; ++i)
                *(float4*)&e_s[(qg * 4 + i) * 904 + pl] =
                    make_float4(acc[i][0], acc[i][1], acc[i][2], acc[i][3]);
        }
    }
    __syncthreads();

    // ---- Weighted softmax: w[p] = cnt(y)*cnt(x)*exp(e - m) ----
    {
        const int qi = t >> 4, j = t & 15;         // 16 lanes per query
        float* er = &e_s[qi * 904];
        float m = -1e30f;
        for (int p = j; p < PP; p += 16) m = fmaxf(m, er[p]);
        #pragma unroll
        for (int off = 8; off; off >>= 1) m = fmaxf(m, __shfl_xor(m, off));
        float s = 0.f;
        for (int p = j; p < PP; p += 16) {
            const int y  = p / PW;
            const int xw = p - y * PW;
            const float cy = (float)imin3(y + 1, PW - y, 7);
            const float cx = (float)imin3(xw + 1, PW - xw, 7);
            const float w = cy * cx * __expf(er[p] - m);
            er[p] = w;
            s += w;
        }
        #pragma unroll
        for (int off = 8; off; off >>= 1) s += __shfl_xor(s, off);
        if (j == 0) red[qi] = s;
    }
    __syncthreads();

    // ---- Phase 2: PV, p-split x4, v streamed as float4 rows from global ----
    const int dg = t & 15, qg2 = (t >> 4) & 3, ps = t >> 6;
    float po[4][4] = {};                           // [i -> query qg2+4i][jd]
    {
        const float* vbase = &vT[hd * PP * HDIM];
        const int pend = ps * 225 + 225;
        #pragma unroll 4
        for (int p = ps * 225; p < pend; ++p) {
            const float4 vv = *(const float4*)&vbase[p * HDIM + dg * 4];
            const float w0 = e_s[(qg2 + 0)  * 904 + p];
            const float w1 = e_s[(qg2 + 4)  * 904 + p];
            const float w2 = e_s[(qg2 + 8)  * 904 + p];
            const float w3 = e_s[(qg2 + 12) * 904 + p];
            po[0][0] = fmaf(w0, vv.x, po[0][0]);
            po[0][1] = fmaf(w0, vv.y, po[0][1]);
            po[0][2] = fmaf(w0, vv.z, po[0][2]);
            po[0][3] = fmaf(w0, vv.w, po[0][3]);
            po[1][0] = fmaf(w1, vv.x, po[1][0]);
            po[1][1] = fmaf(w1, vv.y, po[1][1]);
            po[1][2] = fmaf(w1, vv.z, po[1][2]);
            po[1][3] = fmaf(w1, vv.w, po[1][3]);
            po[2][0] = fmaf(w2, vv.x, po[2][0]);
            po[2][1] = fmaf(w2, vv.y, po[2][1]);
            po[2][2] = fmaf(w2, vv.z, po[2][2]);
            po[2][3] = fmaf(w2, vv.w, po[2][3]);
            po[3][0] = fmaf(w3, vv.x, po[3][0]);
            po[3][1] = fmaf(w3, vv.y, po[3][1]);
            po[3][2] = fmaf(w3, vv.z, po[3][2]);
            po[3][3] = fmaf(w3, vv.w, po[3][3]);
        }
    }
    __syncthreads();                               // weights no longer needed

    // partial reduction over the 4 p-slices through LDS (reuse e_s)
    float* scratch = e_s;                          // 16 KB of the 57.8 KB buffer
    #pragma unroll
    for (int i = 0; i < 4; ++i)
        *(float4*)&scratch[t * 16 + i * 4] =
            make_float4(po[i][0], po[i][1], po[i][2], po[i][3]);
    __syncthreads();

    // ---- Epilogue: out = gamma * (PV / l) + x ; float4 stores ----
    {
        const int d = t >> 2;                      // 0..63
        const int qb4 = (t & 3) * 4;               // 4 consecutive queries
        const int dgi = d >> 2, jd = d & 3;
        const float g = gamma[0];
        float vals[4];
        #pragma unroll
        for (int m = 0; m < 4; ++m) {
            const int qi = qb4 + m;
            const int qr = qi & 3;                 // qg2 of writer
            const int qq = qi >> 2;                // i of writer
            float ssum = 0.f;
            #pragma unroll
            for (int psn = 0; psn < 4; ++psn)
                ssum += scratch[(dgi + 16 * qr + 64 * psn) * 16 + qq * 4 + jd];
            vals[m] = ssum / red[qi];
        }
        const int gi = (hd * HDIM + d) * HW + q0 + qb4;
        const float4 xi = *(const float4*)&x[gi];
        float4 r;
        r.x = fmaf(g, vals[0], xi.x);
        r.y = fmaf(g, vals[1], xi.y);
        r.z = fmaf(g, vals[2], xi.z);
        r.w = fmaf(g, vals[3], xi.w);
        *(float4*)&out[gi] = r;
    }
}

// ---------------------------------------------------------------------------
extern "C" void kernel_launch(void* const* d_in, const int* in_sizes, int n_in,
                              void* d_out, int out_size, void* d_ws, size_t ws_size,
                              hipStream_t stream) {
    const float* x     = (const float*)d_in[0];
    const float* Wq    = (const float*)d_in[1];
    const float* bq    = (const float*)d_in[2];
    const float* Wk    = (const float*)d_in[3];
    const float* bk    = (const float*)d_in[4];
    const float* Wv    = (const float*)d_in[5];
    const float* bv    = (const float*)d_in[6];
    const float* gamma = (const float*)d_in[7];
    float* out = (float*)d_out;

    float* ws = (float*)d_ws;
    float* qT = ws;                                // 8*576*64   = 294912 floats
    float* kM = ws + 294912;                       // 512*900    = 460800 floats
    float* vT = ws + 294912 + 460800;              // 8*900*64   = 460800 floats
                                                   // total 4.87 MB of workspace

    qkv_proj<<<dim3(15, 8, 3), 256, 0, stream>>>(x, Wq, bq, Wk, bk, Wv, bv,
                                                 qT, kM, vT);
    attn<<<dim3(36, 8), 256, 0, stream>>>(qT, kM, vT, x, gamma, out);
}

// Round 2
// 142.140 us; speedup vs baseline: 1.2293x; 1.2293x over previous
//
#include <hip/hip_runtime.h>

// Problem constants
#define HW   576      // 24*24 pixels
#define CC   512      // channels
#define PW   30       // padded H/W
#define PP   900      // 30*30 distinct padded positions
#define PPAD 904      // kM row stride (multiple of 8 for 16B bf16 loads)

typedef float f32x4 __attribute__((ext_vector_type(4)));
typedef short s16x8 __attribute__((ext_vector_type(8)));

__device__ __forceinline__ unsigned short f2bf(float f) {
    unsigned u = __float_as_uint(f);                      // RNE fp32->bf16
    return (unsigned short)((u + 0x7FFFu + ((u >> 16) & 1u)) >> 16);
}
__device__ __forceinline__ float bflo(unsigned u) { return __uint_as_float(u << 16); }
__device__ __forceinline__ float bfhi(unsigned u) { return __uint_as_float(u & 0xFFFF0000u); }

// ---------------------------------------------------------------------------
// Kernel 1: Q/K/V 1x1-conv projections as bf16 MFMA GEMMs (fp32 accumulate).
// Unified over sel (grid.z): one operand is W (staged direct, [o][k]), the
// other is x / reflect-padded x (staged transposed, [pix][k]).
//   sel 0: D[pix][o]  -> qT bf16 [head][pix][64]
//   sel 1: D[o][p]    -> kM bf16 [chan][904]   (cols 900..903 zeroed)
//   sel 2: D[p][o]    -> vT bf16 [head][p][64]
// grid (15, 8, 3), block 256 (4 waves, each 32x32 of the 64x64 tile).
// ---------------------------------------------------------------------------
__global__ __launch_bounds__(256) void qkv_mfma(
    const float* __restrict__ x,
    const float* __restrict__ Wq, const float* __restrict__ bq,
    const float* __restrict__ Wk, const float* __restrict__ bk,
    const float* __restrict__ Wv, const float* __restrict__ bv,
    unsigned short* __restrict__ qT, unsigned short* __restrict__ kM,
    unsigned short* __restrict__ vT)
{
    const int sel = blockIdx.z;
    const int bx = blockIdx.x, by = blockIdx.y;
    if (sel == 0 && bx >= 9) return;              // q: only 9 column tiles
    const int big0 = bx * 64;

    const float* Wsel = (sel == 0) ? Wq : (sel == 1) ? Wk : Wv;
    const float* bias = (sel == 0) ? bq : (sel == 1) ? bk : bv;

    __shared__ __align__(16) unsigned short Wl[64 * 40];  // [o][k], stride 40 bf16
    __shared__ __align__(16) unsigned short Xl[64 * 40];  // [pix][k]
    __shared__ int smap[64];

    const int t = threadIdx.x;
    if (t < 64) {                                 // reflect-pad gather map
        int pp = big0 + t;
        int src;
        if (sel == 0) src = pp;
        else {
            if (pp >= PP) pp = PP - 1;
            int y  = pp / PW, xw = pp - y * PW;
            int iy = y - 3;  iy = (iy < 0) ? -iy : (iy > 23 ? 46 - iy : iy);
            int ix = xw - 3; ix = (ix < 0) ? -ix : (ix > 23 ? 46 - ix : ix);
            src = iy * 24 + ix;
        }
        smap[t] = src;
    }
    __syncthreads();

    const int wrow = t >> 2, wk = (t & 3) * 8;    // W staging: 64 rows x 32 k
    const float* Wrow = Wsel + (size_t)(by * 64 + wrow) * CC + wk;
    const int px4 = (t & 15) * 4, k2 = (t >> 4) * 2;  // X staging: 64 px x 32 k

    float wr[8], xr[8];
    auto loadW = [&](int k0) {
        const float4 a4 = *(const float4*)(Wrow + k0);
        const float4 b4 = *(const float4*)(Wrow + k0 + 4);
        wr[0] = a4.x; wr[1] = a4.y; wr[2] = a4.z; wr[3] = a4.w;
        wr[4] = b4.x; wr[5] = b4.y; wr[6] = b4.z; wr[7] = b4.w;
    };
    auto loadX = [&](int k0) {
        const float* r0 = x + (size_t)(k0 + k2) * HW;
        const float* r1 = r0 + HW;
        if (sel == 0) {
            const float4 a4 = *(const float4*)(r0 + big0 + px4);
            const float4 b4 = *(const float4*)(r1 + big0 + px4);
            xr[0] = a4.x; xr[1] = a4.y; xr[2] = a4.z; xr[3] = a4.w;
            xr[4] = b4.x; xr[5] = b4.y; xr[6] = b4.z; xr[7] = b4.w;
        } else {
            #pragma unroll
            for (int i = 0; i < 4; ++i) {
                const int s = smap[px4 + i];
                xr[i]     = r0[s];
                xr[4 + i] = r1[s];
            }
        }
    };

    loadW(0);
    loadX(0);

    f32x4 acc[2][2];
    #pragma unroll
    for (int i = 0; i < 2; ++i)
        #pragma unroll
        for (int j = 0; j < 2; ++j)
            acc[i][j] = (f32x4){0.f, 0.f, 0.f, 0.f};

    const int lane = t & 63, wv = t >> 6;
    const int wm = (wv >> 1) * 32, wn = (wv & 1) * 32;
    const int fr = lane & 15, fq = lane >> 4;     // frag row / k-quad

    const unsigned short* At = (sel == 1) ? Wl : Xl;
    const unsigned short* Bt = (sel == 1) ? Xl : Wl;

    for (int it = 0; it < 16; ++it) {
        // commit prefetched regs to LDS (fp32 -> bf16)
        {
            s16x8 w8;
            #pragma unroll
            for (int j = 0; j < 8; ++j) w8[j] = (short)f2bf(wr[j]);
            *(s16x8*)&Wl[wrow * 40 + wk] = w8;
            #pragma unroll
            for (int i = 0; i < 4; ++i) {
                unsigned u = (unsigned)f2bf(xr[i]) | ((unsigned)f2bf(xr[4 + i]) << 16);
                *(unsigned*)&Xl[(px4 + i) * 40 + k2] = u;
            }
        }
        __syncthreads();
        if (it < 15) { loadW((it + 1) * 32); loadX((it + 1) * 32); }  // overlap MFMA
        const s16x8 a0 = *(const s16x8*)&At[(wm +  0 + fr) * 40 + fq * 8];
        const s16x8 a1 = *(const s16x8*)&At[(wm + 16 + fr) * 40 + fq * 8];
        const s16x8 b0 = *(const s16x8*)&Bt[(wn +  0 + fr) * 40 + fq * 8];
        const s16x8 b1 = *(const s16x8*)&Bt[(wn + 16 + fr) * 40 + fq * 8];
        acc[0][0] = __builtin_amdgcn_mfma_f32_16x16x32_bf16(a0, b0, acc[0][0], 0, 0, 0);
        acc[0][1] = __builtin_amdgcn_mfma_f32_16x16x32_bf16(a0, b1, acc[0][1], 0, 0, 0);
        acc[1][0] = __builtin_amdgcn_mfma_f32_16x16x32_bf16(a1, b0, acc[1][0], 0, 0, 0);
        acc[1][1] = __builtin_amdgcn_mfma_f32_16x16x32_bf16(a1, b1, acc[1][1], 0, 0, 0);
        __syncthreads();
    }

    // epilogue: C/D layout col=lane&15, row=(lane>>4)*4+reg
    #pragma unroll
    for (int mi = 0; mi < 2; ++mi)
        #pragma unroll
        for (int ni = 0; ni < 2; ++ni)
            #pragma unroll
            for (int r = 0; r < 4; ++r) {
                const float vacc = acc[mi][ni][r];
                const int m = wm + mi * 16 + fq * 4 + r;
                const int n = wn + ni * 16 + fr;
                if (sel == 0) {
                    const int o = by * 64 + n;
                    qT[((size_t)by * HW + big0 + m) * 64 + n] = f2bf(vacc + bias[o]);
                } else if (sel == 2) {
                    const int p = big0 + m;
                    if (p < PP) {
                        const int o = by * 64 + n;
                        vT[((size_t)by * PP + p) * 64 + n] = f2bf(vacc + bias[o]);
                    }
                } else {
                    const int o = by * 64 + m;
                    const int p = big0 + n;
                    if (p < PP)        kM[(size_t)o * PPAD + p] = f2bf(vacc + bias[o]);
                    else if (p < PPAD) kM[(size_t)o * PPAD + p] = 0;
                }
            }
}

// ---------------------------------------------------------------------------
// Kernel 2: fused attention, multiplicity-weighted softmax over 900 distinct
// keys. 8 queries/block -> grid (72, 8) = 576 blocks; bf16 k/v halves the
// global stream. LDS ~31 KB -> 5 blocks/CU possible.
// ---------------------------------------------------------------------------
__global__ __launch_bounds__(256) void attn2(
    const unsigned short* __restrict__ qT, const unsigned short* __restrict__ kM,
    const unsigned short* __restrict__ vT, const float* __restrict__ x,
    const float* __restrict__ gamma, float* __restrict__ out)
{
    const int hd = blockIdx.y;
    const int q0 = blockIdx.x * 8;
    const int t = threadIdx.x;

    __shared__ __align__(16) float q_t[64 * 8];   // [d][qi]
    __shared__ __align__(16) float e_s[8 * PPAD]; // energies -> weights [qi][p]
    __shared__ float red[8];

    // stage q (bf16 -> fp32, transposed)
    if (t < 64) {
        const int qi = t >> 3, dq = (t & 7) * 8;
        const uint4 u = *(const uint4*)&qT[((size_t)hd * HW + q0 + qi) * 64 + dq];
        q_t[(dq + 0) * 8 + qi] = bflo(u.x); q_t[(dq + 1) * 8 + qi] = bfhi(u.x);
        q_t[(dq + 2) * 8 + qi] = bflo(u.y); q_t[(dq + 3) * 8 + qi] = bfhi(u.y);
        q_t[(dq + 4) * 8 + qi] = bflo(u.z); q_t[(dq + 5) * 8 + qi] = bfhi(u.z);
        q_t[(dq + 6) * 8 + qi] = bflo(u.w); q_t[(dq + 7) * 8 + qi] = bfhi(u.w);
    }
    __syncthreads();

    // ---- Phase 1: e[q][p] = q . k ; thread = 8p x 4q, single sweep ----
    {
        const int po = t & 31, qq = (t >> 5) & 1, sw = t >> 6;
        const int p0 = sw * 256 + po * 8;
        if (p0 < PPAD) {
            float acc[4][8] = {};
            const unsigned short* kb = &kM[(size_t)(hd * 64) * PPAD + p0];
            #pragma unroll 4
            for (int d = 0; d < 64; ++d) {
                const uint4 u = *(const uint4*)&kb[(size_t)d * PPAD];
                float kv[8] = {bflo(u.x), bfhi(u.x), bflo(u.y), bfhi(u.y),
                               bflo(u.z), bfhi(u.z), bflo(u.w), bfhi(u.w)};
                const float4 qv = *(const float4*)&q_t[d * 8 + qq * 4];
                const float qa[4] = {qv.x, qv.y, qv.z, qv.w};
                #pragma unroll
                for (int qi = 0; qi < 4; ++qi)
                    #pragma unroll
                    for (int j = 0; j < 8; ++j)
                        acc[qi][j] = fmaf(qa[qi], kv[j], acc[qi][j]);
            }
            #pragma unroll
            for (int qi = 0; qi < 4; ++qi) {
                *(float4*)&e_s[(qq * 4 + qi) * PPAD + p0] =
                    make_float4(acc[qi][0], acc[qi][1], acc[qi][2], acc[qi][3]);
                *(float4*)&e_s[(qq * 4 + qi) * PPAD + p0 + 4] =
                    make_float4(acc[qi][4], acc[qi][5], acc[qi][6], acc[qi][7]);
            }
        }
    }
    __syncthreads();

    // ---- Weighted softmax: w[p] = cnt(y)*cnt(x)*exp(e-m); 32 lanes/query ----
    {
        const int qi = t >> 5, j = t & 31;
        float* er = &e_s[qi * PPAD];
        float m = -1e30f;
        for (int p = j; p < PPAD; p += 32) m = fmaxf(m, er[p]);
        #pragma unroll
        for (int off = 16; off; off >>= 1) m = fmaxf(m, __shfl_xor(m, off));
        float s = 0.f;
        for (int p = j; p < PPAD; p += 32) {
            const int y  = p / PW;
            const int xw = p - y * PW;
            int cyi = y + 1;  if (PW - y < cyi) cyi = PW - y;  if (cyi > 7) cyi = 7;
            int cxi = xw + 1; if (PW - xw < cxi) cxi = PW - xw; if (cxi > 7) cxi = 7;
            const float w = (float)(cyi * cxi) * __expf(er[p] - m);  // 0 for p>=900
            er[p] = w;
            s += w;
        }
        #pragma unroll
        for (int off = 16; off; off >>= 1) s += __shfl_xor(s, off);
        if (j == 0) red[qi] = s;
    }
    __syncthreads();

    // ---- Phase 2: PV ; thread = 8d x 2q x (1/8 of p) ----
    const int dg = t & 7, qg = (t >> 3) & 3, ps = t >> 5;
    float po2[2][8] = {};
    {
        const unsigned short* vb = &vT[(size_t)hd * PP * 64 + dg * 8];
        const int pbeg = ps * 113;
        const int pend = (pbeg + 113 < PP) ? pbeg + 113 : PP;
        for (int p = pbeg; p < pend; ++p) {
            const uint4 u = *(const uint4*)&vb[(size_t)p * 64];
            const float vv[8] = {bflo(u.x), bfhi(u.x), bflo(u.y), bfhi(u.y),
                                 bflo(u.z), bfhi(u.z), bflo(u.w), bfhi(u.w)};
            const float w0 = e_s[(qg * 2 + 0) * PPAD + p];
            const float w1 = e_s[(qg * 2 + 1) * PPAD + p];
            #pragma unroll
            for (int j = 0; j < 8; ++j) {
                po2[0][j] = fmaf(w0, vv[j], po2[0][j]);
                po2[1][j] = fmaf(w1, vv[j], po2[1][j]);
            }
        }
    }
    __syncthreads();                              // weights no longer needed

    // partial reduction over the 8 p-slices (reuse e_s as [ps][q][d])
    float* sc = e_s;
    #pragma unroll
    for (int qi2 = 0; qi2 < 2; ++qi2) {
        const int qn = qg * 2 + qi2;
        *(float4*)&sc[ps * 512 + qn * 64 + dg * 8] =
            make_float4(po2[qi2][0], po2[qi2][1], po2[qi2][2], po2[qi2][3]);
        *(float4*)&sc[ps * 512 + qn * 64 + dg * 8 + 4] =
            make_float4(po2[qi2][4], po2[qi2][5], po2[qi2][6], po2[qi2][7]);
    }
    __syncthreads();

    // ---- Epilogue: out = gamma * PV/l + x ----
    {
        const int dd = t >> 2, qp = (t & 3) * 2;
        const float g = gamma[0];
        float o0 = 0.f, o1 = 0.f;
        #pragma unroll
        for (int s2 = 0; s2 < 8; ++s2) {
            o0 += sc[s2 * 512 + (qp + 0) * 64 + dd];
            o1 += sc[s2 * 512 + (qp + 1) * 64 + dd];
        }
        o0 /= red[qp];
        o1 /= red[qp + 1];
        const size_t gi = (size_t)(hd * 64 + dd) * HW + q0 + qp;
        const float2 xi = *(const float2*)&x[gi];
        float2 r2;
        r2.x = fmaf(g, o0, xi.x);
        r2.y = fmaf(g, o1, xi.y);
        *(float2*)&out[gi] = r2;
    }
}

// ---------------------------------------------------------------------------
extern "C" void kernel_launch(void* const* d_in, const int* in_sizes, int n_in,
                              void* d_out, int out_size, void* d_ws, size_t ws_size,
                              hipStream_t stream) {
    const float* x     = (const float*)d_in[0];
    const float* Wq    = (const float*)d_in[1];
    const float* bq    = (const float*)d_in[2];
    const float* Wk    = (const float*)d_in[3];
    const float* bk    = (const float*)d_in[4];
    const float* Wv    = (const float*)d_in[5];
    const float* bv    = (const float*)d_in[6];
    const float* gamma = (const float*)d_in[7];
    float* out = (float*)d_out;

    unsigned short* ws = (unsigned short*)d_ws;
    unsigned short* qT = ws;                       // 8*576*64 = 294912 bf16
    unsigned short* kM = ws + 294912;              // 512*904  = 462848 bf16
    unsigned short* vT = ws + 294912 + 462848;     // 8*900*64 = 460800 bf16
                                                   // total ~2.44 MB

    qkv_mfma<<<dim3(15, 8, 3), 256, 0, stream>>>(x, Wq, bq, Wk, bk, Wv, bv,
                                                 qT, kM, vT);
    attn2<<<dim3(72, 8), 256, 0, stream>>>(qT, kM, vT, x, gamma, out);
}

// Round 3
// 109.152 us; speedup vs baseline: 1.6009x; 1.3022x over previous
//
#include <hip/hip_runtime.h>

// Problem constants
#define HW   576      // 24*24 pixels
#define CC   512      // channels
#define PW   30       // padded H/W
#define PPK  1024     // padded p rows for kT / vP (900 real + zeros)
#define NS   4        // p slices
#define SP   256      // p per slice

typedef float f32x4 __attribute__((ext_vector_type(4)));
typedef short s16x8 __attribute__((ext_vector_type(8)));

__device__ __forceinline__ unsigned short f2bf(float f) {
    unsigned u = __float_as_uint(f);                      // RNE fp32->bf16
    return (unsigned short)((u + 0x7FFFu + ((u >> 16) & 1u)) >> 16);
}
__device__ __forceinline__ float bf2f(unsigned short h) {
    return __uint_as_float((unsigned)h << 16);
}

// Workspace byte offsets (total 5193728 B; Op aliases xb+Wb, dead by then)
#define OFF_QT 0u         // bf16 [8][576][64]
#define OFF_KT 589824u    // bf16 [8][1024][64]  (p rows, pad zeroed)
#define OFF_VP 1638400u   // bf16 [8][64][1024]  (V^T, pad zeroed)
#define OFF_MP 2686976u   // f32  [8][4][576]
#define OFF_LP 2760704u   // f32  [8][4][576]
#define OFF_OP 2834432u   // bf16 [8][4][576][64]
#define OFF_XB 2834432u   // bf16 [512][576]   (aliases Op - consumed before)
#define OFF_WB 3424256u   // bf16 [3][512][512]

// ---------------------------------------------------------------------------
// Kernel 0: one-shot fp32 -> bf16 conversion of x and Wq/Wk/Wv.
// ---------------------------------------------------------------------------
__global__ __launch_bounds__(256) void cvt_bf16(
    const float* __restrict__ x, const float* __restrict__ Wq,
    const float* __restrict__ Wk, const float* __restrict__ Wv,
    unsigned short* __restrict__ xb, unsigned short* __restrict__ wb)
{
    const int b = blockIdx.x, t = threadIdx.x;
    if (b < 288) {                                 // x: 288*1024 = 294912 exact
        const int i = (b * 256 + t) * 4;
        const float4 v = *(const float4*)&x[i];
        ushort4 o;
        o.x = f2bf(v.x); o.y = f2bf(v.y); o.z = f2bf(v.z); o.w = f2bf(v.w);
        *(ushort4*)&xb[i] = o;
    } else {                                       // W: 768*1024 = 786432 exact
        const int wi = ((b - 288) * 256 + t) * 4;
        const int sel = wi >> 18;                  // / 262144
        const int off = wi & 262143;
        const float* src = (sel == 0) ? Wq : (sel == 1) ? Wk : Wv;
        const float4 v = *(const float4*)&src[off];
        ushort4 o;
        o.x = f2bf(v.x); o.y = f2bf(v.y); o.z = f2bf(v.z); o.w = f2bf(v.w);
        *(ushort4*)&wb[wi] = o;
    }
}

// ---------------------------------------------------------------------------
// Kernel 1: Q/K/V 1x1-conv projections, bf16 MFMA, double-buffered LDS.
//   sel 0: D[pix][o]  -> qT [head][pix][64]
//   sel 1: D[p][o]    -> kT [head][p(1024)][64], p>=900 zeroed
//   sel 2: D[o][p]    -> vP [head][64][p(1024)], p>=900 zeroed
// grid (16, 8, 3), block 256 (4 waves, each 32x32 of the 64x64 tile).
// ---------------------------------------------------------------------------
__global__ __launch_bounds__(256) void qkv_mfma(
    const unsigned short* __restrict__ xb, const unsigned short* __restrict__ wb,
    const float* __restrict__ bq, const float* __restrict__ bk,
    const float* __restrict__ bv,
    unsigned short* __restrict__ qT, unsigned short* __restrict__ kT,
    unsigned short* __restrict__ vP)
{
    const int sel = blockIdx.z;
    const int bx = blockIdx.x, by = blockIdx.y;
    if (sel == 0 && bx >= 9) return;              // q: 576 cols = 9 tiles
    const int big0 = bx * 64;
    const float* bias = (sel == 0) ? bq : (sel == 1) ? bk : bv;

    __shared__ __align__(16) unsigned short Wl[2][64 * 40];
    __shared__ __align__(16) unsigned short Xl[2][64 * 40];
    __shared__ int smap[64];

    const int t = threadIdx.x;
    if (t < 64) {                                 // reflect-pad gather map
        int pp = big0 + t;
        int src;
        if (sel == 0) src = pp;
        else {
            if (pp >= 900) pp = 899;
            int y  = pp / PW, xw = pp - y * PW;
            int iy = y - 3;  iy = (iy < 0) ? -iy : (iy > 23 ? 46 - iy : iy);
            int ix = xw - 3; ix = (ix < 0) ? -ix : (ix > 23 ? 46 - ix : ix);
            src = iy * 24 + ix;
        }
        smap[t] = src;
    }
    __syncthreads();

    const int wrow = t >> 2, wk_ = (t & 3) * 8;   // W staging: 64 rows x 32 k
    const unsigned short* Wrow =
        wb + (size_t)sel * 262144 + (size_t)(by * 64 + wrow) * CC + wk_;
    const int px4 = (t & 15) * 4, k2 = (t >> 4) * 2;  // X: 64 px x 32 k

    s16x8 wreg;
    unsigned short xreg[8];
    auto loadW = [&](int k0) { wreg = *(const s16x8*)(Wrow + k0); };
    auto loadX = [&](int k0) {
        const unsigned short* r0 = xb + (size_t)(k0 + k2) * HW;
        const unsigned short* r1 = r0 + HW;
        if (sel == 0) {
            *(ushort4*)&xreg[0] = *(const ushort4*)(r0 + big0 + px4);
            *(ushort4*)&xreg[4] = *(const ushort4*)(r1 + big0 + px4);
        } else {
            #pragma unroll
            for (int i = 0; i < 4; ++i) {
                const int s = smap[px4 + i];
                xreg[i]     = r0[s];
                xreg[4 + i] = r1[s];
            }
        }
    };
    auto commit = [&](int bi) {
        *(s16x8*)&Wl[bi][wrow * 40 + wk_] = wreg;
        #pragma unroll
        for (int i = 0; i < 4; ++i) {
            unsigned u = (unsigned)xreg[i] | ((unsigned)xreg[4 + i] << 16);
            *(unsigned*)&Xl[bi][(px4 + i) * 40 + k2] = u;
        }
    };

    loadW(0);  loadX(0);
    commit(0);
    loadW(32); loadX(32);

    f32x4 acc[2][2];
    #pragma unroll
    for (int i = 0; i < 2; ++i)
        #pragma unroll
        for (int j = 0; j < 2; ++j) acc[i][j] = (f32x4){0.f, 0.f, 0.f, 0.f};

    const int lane = t & 63, wv = t >> 6;
    const int wm = (wv >> 1) * 32, wn = (wv & 1) * 32;
    const int fr = lane & 15, fq = lane >> 4;

    const unsigned short* Abase = (sel == 2) ? &Wl[0][0] : &Xl[0][0];
    const unsigned short* Bbase = (sel == 2) ? &Xl[0][0] : &Wl[0][0];

    __syncthreads();                              // buf0 visible
    for (int it = 0; it < 16; ++it) {
        const int cur = it & 1;
        if (it < 15) commit(1 - cur);             // safe: barrier ended it-1
        if (it < 14) { loadW((it + 2) * 32); loadX((it + 2) * 32); }
        const unsigned short* A = Abase + cur * 2560;
        const unsigned short* B = Bbase + cur * 2560;
        const s16x8 a0 = *(const s16x8*)&A[(wm +  0 + fr) * 40 + fq * 8];
        const s16x8 a1 = *(const s16x8*)&A[(wm + 16 + fr) * 40 + fq * 8];
        const s16x8 b0 = *(const s16x8*)&B[(wn +  0 + fr) * 40 + fq * 8];
        const s16x8 b1 = *(const s16x8*)&B[(wn + 16 + fr) * 40 + fq * 8];
        acc[0][0] = __builtin_amdgcn_mfma_f32_16x16x32_bf16(a0, b0, acc[0][0], 0, 0, 0);
        acc[0][1] = __builtin_amdgcn_mfma_f32_16x16x32_bf16(a0, b1, acc[0][1], 0, 0, 0);
        acc[1][0] = __builtin_amdgcn_mfma_f32_16x16x32_bf16(a1, b0, acc[1][0], 0, 0, 0);
        acc[1][1] = __builtin_amdgcn_mfma_f32_16x16x32_bf16(a1, b1, acc[1][1], 0, 0, 0);
        __syncthreads();
    }

    // epilogue: C/D layout col=lane&15, row=(lane>>4)*4+reg
    #pragma unroll
    for (int mi = 0; mi < 2; ++mi)
        #pragma unroll
        for (int ni = 0; ni < 2; ++ni)
            #pragma unroll
            for (int r = 0; r < 4; ++r) {
                const float vacc = acc[mi][ni][r];
                const int m = wm + mi * 16 + fq * 4 + r;
                const int n = wn + ni * 16 + fr;
                if (sel == 0) {
                    qT[((size_t)by * HW + big0 + m) * 64 + n] =
                        f2bf(vacc + bias[by * 64 + n]);
                } else if (sel == 1) {            // A=X: m = p, n = chan
                    const int p = big0 + m;
                    kT[((size_t)by * PPK + p) * 64 + n] =
                        (p < 900) ? f2bf(vacc + bias[by * 64 + n]) : (unsigned short)0;
                } else {                          // A=W: m = chan, n = p
                    const int p = big0 + n;
                    vP[((size_t)by * 64 + m) * PPK + p] =
                        (p < 900) ? f2bf(vacc + bias[by * 64 + m]) : (unsigned short)0;
                }
            }
}

// ---------------------------------------------------------------------------
// Kernel 2: MFMA attention, split-p partials. Block = (head, 16q, 256p slice);
// grid (36, 4, 8) = 1152 blocks, 4 waves. Writes per-slice (m, l, O) partials.
// E^T tiles: A-frag = kT rows (m=p), B-frag = qT rows (n=q): contiguous 16B
// loads straight from L2. Weights round-trip LDS (bf16) into PV A-operand
// layout; PV B-frags are contiguous rows of vP (V transposed). LDS ~10 KB.
// ---------------------------------------------------------------------------
__global__ __launch_bounds__(256) void attn3(
    const unsigned short* __restrict__ qT, const unsigned short* __restrict__ kT,
    const unsigned short* __restrict__ vP, float* __restrict__ mP,
    float* __restrict__ lP, unsigned short* __restrict__ Op)
{
    const int q0 = blockIdx.x * 16;
    const int s  = blockIdx.y;
    const int hd = blockIdx.z;
    const int t  = threadIdx.x;
    const int lane = t & 63, w = t >> 6;
    const int fr = lane & 15, u = lane >> 4;

    __shared__ float cnt_s[SP];                   // multiplicity table
    __shared__ __align__(16) unsigned short Wl[16 * 272];  // weights [q][p+pad]
    __shared__ float mw[64], lw[64];

    if (t < SP) {                                 // cnt(y)*cnt(x), 0 for pads
        const int p = s * SP + t;
        float c = 0.f;
        if (p < 900) {
            const int y = p / PW, xw = p - y * PW;
            int cy = y + 1;  if (PW - y  < cy) cy = PW - y;  if (cy > 7) cy = 7;
            int cx = xw + 1; if (PW - xw < cx) cx = PW - xw; if (cx > 7) cx = 7;
            c = (float)(cy * cx);
        }
        cnt_s[t] = c;
    }

    // q B-frags (shared across this wave's p-tiles)
    const unsigned short* qrow = qT + ((size_t)hd * HW + q0 + fr) * 64 + u * 8;
    const s16x8 b0 = *(const s16x8*)qrow;
    const s16x8 b1 = *(const s16x8*)(qrow + 32);

    // QK: 4 E^T tiles (16p x 16q) per wave
    f32x4 e[4];
    #pragma unroll
    for (int t4 = 0; t4 < 4; ++t4) {
        const unsigned short* krow =
            kT + ((size_t)hd * PPK + s * SP + w * 64 + t4 * 16 + fr) * 64 + u * 8;
        const s16x8 a0 = *(const s16x8*)krow;
        const s16x8 a1 = *(const s16x8*)(krow + 32);
        f32x4 a = (f32x4){0.f, 0.f, 0.f, 0.f};
        a = __builtin_amdgcn_mfma_f32_16x16x32_bf16(a0, b0, a, 0, 0, 0);
        a = __builtin_amdgcn_mfma_f32_16x16x32_bf16(a1, b1, a, 0, 0, 0);
        e[t4] = a;
    }

    // per-q max (all 16 regs share q = fr; cross-quad via 2 shuffles)
    float m = -1e30f;
    #pragma unroll
    for (int t4 = 0; t4 < 4; ++t4)
        #pragma unroll
        for (int r = 0; r < 4; ++r) m = fmaxf(m, e[t4][r]);
    m = fmaxf(m, __shfl_xor(m, 16));
    m = fmaxf(m, __shfl_xor(m, 32));
    if (lane < 16) mw[w * 16 + lane] = m;
    __syncthreads();
    const float mq = fmaxf(fmaxf(mw[fr], mw[16 + fr]), fmaxf(mw[32 + fr], mw[48 + fr]));

    // weights = cnt * exp(e - mq): bf16 into Wl; per-q partial sums
    float sum = 0.f;
    #pragma unroll
    for (int t4 = 0; t4 < 4; ++t4) {
        unsigned short wb4[4];
        #pragma unroll
        for (int r = 0; r < 4; ++r) {
            const float wv2 = cnt_s[w * 64 + t4 * 16 + u * 4 + r] *
                              __expf(e[t4][r] - mq);
            sum += wv2;
            wb4[r] = f2bf(wv2);
        }
        const int ho = fr * 272 + w * 64 + t4 * 16 + u * 4;
        *(unsigned*)&Wl[ho]     = (unsigned)wb4[0] | ((unsigned)wb4[1] << 16);
        *(unsigned*)&Wl[ho + 2] = (unsigned)wb4[2] | ((unsigned)wb4[3] << 16);
    }
    sum += __shfl_xor(sum, 16);
    sum += __shfl_xor(sum, 32);
    if (lane < 16) lw[w * 16 + lane] = sum;
    __syncthreads();

    if (t < 16) {                                 // store per-slice stats
        const float lq = lw[t] + lw[16 + t] + lw[32 + t] + lw[48 + t];
        const float mq2 = fmaxf(fmaxf(mw[t], mw[16 + t]),
                                fmaxf(mw[32 + t], mw[48 + t]));
        const int si = (hd * NS + s) * HW + q0 + t;
        lP[si] = lq;
        mP[si] = mq2;
    }

    // PV: wave w owns d-tile w; O[16q][16d] over this slice's 256 p
    f32x4 o = (f32x4){0.f, 0.f, 0.f, 0.f};
    const unsigned short* vrow =
        vP + ((size_t)hd * 64 + w * 16 + fr) * PPK + s * SP + u * 8;
    #pragma unroll
    for (int c = 0; c < 8; ++c) {
        const s16x8 aw = *(const s16x8*)&Wl[fr * 272 + c * 32 + u * 8];
        const s16x8 bv2 = *(const s16x8*)(vrow + c * 32);
        o = __builtin_amdgcn_mfma_f32_16x16x32_bf16(aw, bv2, o, 0, 0, 0);
    }
    #pragma unroll
    for (int r = 0; r < 4; ++r) {                 // C layout: row=q, col=d
        const size_t oi =
            ((size_t)(hd * NS + s) * HW + q0 + u * 4 + r) * 64 + w * 16 + fr;
        Op[oi] = f2bf(o[r]);
    }
}

// ---------------------------------------------------------------------------
// Kernel 3: merge the 4 p-slice partials; out = gamma * O/l + x.
// Thread <-> (c, q) with q contiguous: x/out fully coalesced; Op via L2.
// ---------------------------------------------------------------------------
__global__ __launch_bounds__(256) void combine(
    const unsigned short* __restrict__ Op, const float* __restrict__ mP,
    const float* __restrict__ lP, const float* __restrict__ x,
    const float* __restrict__ gamma, float* __restrict__ out)
{
    const int idx = blockIdx.x * 256 + threadIdx.x;   // 294912 total, exact
    const int c = idx / HW, q = idx - c * HW;
    const int hd = c >> 6, d = c & 63;
    const int sb = (hd * NS) * HW + q;
    const float m0 = mP[sb], m1 = mP[sb + HW], m2 = mP[sb + 2 * HW], m3 = mP[sb + 3 * HW];
    const float ms = fmaxf(fmaxf(m0, m1), fmaxf(m2, m3));
    const float a0 = __expf(m0 - ms), a1 = __expf(m1 - ms);
    const float a2 = __expf(m2 - ms), a3 = __expf(m3 - ms);
    const float l = lP[sb] * a0 + lP[sb + HW] * a1 +
                    lP[sb + 2 * HW] * a2 + lP[sb + 3 * HW] * a3;
    const float o =
        bf2f(Op[(size_t)(sb)          * 64 + d]) * a0 +
        bf2f(Op[(size_t)(sb + HW)     * 64 + d]) * a1 +
        bf2f(Op[(size_t)(sb + 2 * HW) * 64 + d]) * a2 +
        bf2f(Op[(size_t)(sb + 3 * HW) * 64 + d]) * a3;
    out[idx] = fmaf(gamma[0], o / l, x[idx]);
}

// ---------------------------------------------------------------------------
extern "C" void kernel_launch(void* const* d_in, const int* in_sizes, int n_in,
                              void* d_out, int out_size, void* d_ws, size_t ws_size,
                              hipStream_t stream) {
    const float* x     = (const float*)d_in[0];
    const float* Wq    = (const float*)d_in[1];
    const float* bq    = (const float*)d_in[2];
    const float* Wk    = (const float*)d_in[3];
    const float* bk    = (const float*)d_in[4];
    const float* Wv    = (const float*)d_in[5];
    const float* bv    = (const float*)d_in[6];
    const float* gamma = (const float*)d_in[7];
    float* out = (float*)d_out;

    char* wsb = (char*)d_ws;
    unsigned short* qT = (unsigned short*)(wsb + OFF_QT);
    unsigned short* kT = (unsigned short*)(wsb + OFF_KT);
    unsigned short* vP = (unsigned short*)(wsb + OFF_VP);
    float*          mP = (float*)(wsb + OFF_MP);
    float*          lP = (float*)(wsb + OFF_LP);
    unsigned short* Op = (unsigned short*)(wsb + OFF_OP);
    unsigned short* xb = (unsigned short*)(wsb + OFF_XB);
    unsigned short* wb = (unsigned short*)(wsb + OFF_WB);

    cvt_bf16<<<dim3(1056), 256, 0, stream>>>(x, Wq, Wk, Wv, xb, wb);
    qkv_mfma<<<dim3(16, 8, 3), 256, 0, stream>>>(xb, wb, bq, bk, bv, qT, kT, vP);
    attn3<<<dim3(36, NS, 8), 256, 0, stream>>>(qT, kT, vP, mP, lP, Op);
    combine<<<dim3(1152), 256, 0, stream>>>(Op, mP, lP, x, gamma, out);
}

// Round 5
// 107.834 us; speedup vs baseline: 1.6204x; 1.0122x over previous
//
#include <hip/hip_runtime.h>

// Problem constants
#define HW   576      // 24*24 pixels
#define CC   512      // channels
#define PW   30       // padded H/W
#define PPK  1024     // padded p rows (900 real + pad)
#define NS   4        // p slices in attn
#define SP   256      // p per slice

typedef float f32x4 __attribute__((ext_vector_type(4)));
typedef short s16x8 __attribute__((ext_vector_type(8)));

__device__ __forceinline__ unsigned short f2bf(float f) {
    unsigned u = __float_as_uint(f);                      // RNE fp32->bf16
    return (unsigned short)((u + 0x7FFFu + ((u >> 16) & 1u)) >> 16);
}
__device__ __forceinline__ float bf2f(unsigned short h) {
    return __uint_as_float((unsigned)h << 16);
}
// reflect-pad row map; p>=900 -> zero row 576 of xT
__device__ __forceinline__ int smapf(int p) {
    if (p >= 900) return 576;
    const int y = p / PW, xw = p - y * PW;
    int iy = y - 3;  iy = (iy < 0) ? -iy : (iy > 23 ? 46 - iy : iy);
    int ix = xw - 3; ix = (ix < 0) ? -ix : (ix > 23 ? 46 - ix : ix);
    return iy * 24 + ix;
}

// Workspace byte offsets (total ~7.36 MB)
#define OFF_QT 0u         // bf16 [8][576][64]
#define OFF_KT 589824u    // bf16 [8][1024][64]
#define OFF_VP 1638400u   // bf16 [8][64][1024]
#define OFF_MP 2686976u   // f32  [8][4][576]
#define OFF_LP 2760704u   // f32  [8][4][576]
#define OFF_OP 2834432u   // bf16 [8][4][576][64]
#define OFF_XT 5193728u   // bf16 [577][512] (row 576 = zeros)
#define OFF_WB 5784576u   // bf16 [3][512][512]

// ---------------------------------------------------------------------------
// Kernel 0: build xT (bf16 transpose of x, LDS-tiled 64x64, + zero row) and
// wb (bf16 copy of Wq/Wk/Wv). grid 457 blocks x 256.
// FIX vs R4: each block now loads/stores the FULL 64x64 tile (4 passes of 16
// rows); R4 filled only rows 0..15 and read uninitialized LDS -> NaN.
// ---------------------------------------------------------------------------
__global__ __launch_bounds__(256) void cvtT(
    const float* __restrict__ x,
    const float* __restrict__ Wq, const float* __restrict__ Wk,
    const float* __restrict__ Wv,
    unsigned short* __restrict__ xT, unsigned short* __restrict__ wb)
{
    const int b = blockIdx.x, t = threadIdx.x;
    if (b < 72) {                                  // transpose: 9 pix-tiles x 8 chan-tiles
        __shared__ float tile[64][65];             // [chan][pix]; stride 65 -> 2-way free
        const int pt = b % 9, ct = b / 9;
        const int p0 = pt * 64, c0 = ct * 64;
        const int tr = t >> 4, tc4 = (t & 15) * 4;
        #pragma unroll
        for (int cr = 0; cr < 4; ++cr) {
            const int row = cr * 16 + tr;          // chan_local
            const float4 v = *(const float4*)&x[(size_t)(c0 + row) * HW + p0 + tc4];
            tile[row][tc4 + 0] = v.x;
            tile[row][tc4 + 1] = v.y;
            tile[row][tc4 + 2] = v.z;
            tile[row][tc4 + 3] = v.w;
        }
        __syncthreads();
        #pragma unroll
        for (int cr = 0; cr < 4; ++cr) {
            const int prow = cr * 16 + tr;         // pix_local
            ushort4 o;
            o.x = f2bf(tile[tc4 + 0][prow]);
            o.y = f2bf(tile[tc4 + 1][prow]);
            o.z = f2bf(tile[tc4 + 2][prow]);
            o.w = f2bf(tile[tc4 + 3][prow]);
            *(ushort4*)&xT[(size_t)(p0 + prow) * CC + c0 + tc4] = o;
        }
    } else if (b == 72) {                          // zero row 576
        if (t < 128) *(ushort4*)&xT[(size_t)576 * CC + t * 4] = (ushort4){0, 0, 0, 0};
    } else {                                       // W convert: 384 blocks x 2048 elems
        const int wi = (b - 73) * 2048 + t * 8;
        const int sel = wi >> 18, off = wi & 262143;
        const float* src = (sel == 0) ? Wq : (sel == 1) ? Wk : Wv;
        const float4 v0 = *(const float4*)&src[off];
        const float4 v1 = *(const float4*)&src[off + 4];
        ushort4 o0, o1;
        o0.x = f2bf(v0.x); o0.y = f2bf(v0.y); o0.z = f2bf(v0.z); o0.w = f2bf(v0.w);
        o1.x = f2bf(v1.x); o1.y = f2bf(v1.y); o1.z = f2bf(v1.z); o1.w = f2bf(v1.w);
        *(ushort4*)&wb[wi]     = o0;
        *(ushort4*)&wb[wi + 4] = o1;
    }
}

// ---------------------------------------------------------------------------
// Kernel 1: Q/K/V projections, barrier-free MFMA. One wave = one 16x32 output
// tile, K=512 in-register; BOTH operands are contiguous 16B row-fragments
// loaded straight from global (xT rows / W rows; reflect-pad via smapf row
// indirection). 2624 waves = 656 blocks x 256 (4 indep waves). No LDS.
//   sel 0 (576 waves):  D[pix][chan]  -> qT [head][pix][64]
//   sel 1 (1024 waves): D[p][chan]    -> kT [head][p][64]   (pad rows: bias, harmless)
//   sel 2 (1024 waves): D[chan][p]    -> vP [head][64][p]   (pad cols: bias, harmless)
// ---------------------------------------------------------------------------
__global__ __launch_bounds__(256) void qkv_direct(
    const unsigned short* __restrict__ xT, const unsigned short* __restrict__ wb,
    const float* __restrict__ bq, const float* __restrict__ bk,
    const float* __restrict__ bv,
    unsigned short* __restrict__ qT, unsigned short* __restrict__ kT,
    unsigned short* __restrict__ vP)
{
    const int t = threadIdx.x;
    const int w = blockIdx.x * 4 + (t >> 6);
    const int lane = t & 63, fr = lane & 15, u = lane >> 4;

    int sel, m0, n0;
    if (w < 576)       { sel = 0; m0 = (w >> 4) << 4;               n0 = (w & 15) << 5; }
    else if (w < 1600) { const int k = w - 576;  sel = 1; m0 = (k >> 4) << 4; n0 = (k & 15) << 5; }
    else               { const int k = w - 1600; sel = 2; m0 = (k >> 5) << 4; n0 = (k & 31) << 5; }

    const unsigned short *A, *B;
    int ar, bn0, bn1;
    if (sel == 0)      { A = xT;          B = wb;          ar = m0 + fr;
                         bn0 = n0 + fr;          bn1 = n0 + 16 + fr; }
    else if (sel == 1) { A = xT;          B = wb + 262144; ar = smapf(m0 + fr);
                         bn0 = n0 + fr;          bn1 = n0 + 16 + fr; }
    else               { A = wb + 524288; B = xT;          ar = m0 + fr;
                         bn0 = smapf(n0 + fr);   bn1 = smapf(n0 + 16 + fr); }

    const unsigned short* Ap  = A + (size_t)ar  * CC + u * 8;
    const unsigned short* Bp0 = B + (size_t)bn0 * CC + u * 8;
    const unsigned short* Bp1 = B + (size_t)bn1 * CC + u * 8;

    f32x4 acc0 = (f32x4){0.f, 0.f, 0.f, 0.f};
    f32x4 acc1 = (f32x4){0.f, 0.f, 0.f, 0.f};
    #pragma unroll 8
    for (int k0 = 0; k0 < CC; k0 += 32) {
        const s16x8 a  = *(const s16x8*)(Ap  + k0);
        const s16x8 b0 = *(const s16x8*)(Bp0 + k0);
        const s16x8 b1 = *(const s16x8*)(Bp1 + k0);
        acc0 = __builtin_amdgcn_mfma_f32_16x16x32_bf16(a, b0, acc0, 0, 0, 0);
        acc1 = __builtin_amdgcn_mfma_f32_16x16x32_bf16(a, b1, acc1, 0, 0, 0);
    }

    // epilogue: C/D layout col(fr)=n, row(u*4+r)=m
    #pragma unroll
    for (int ni = 0; ni < 2; ++ni) {
        const f32x4 acc = ni ? acc1 : acc0;
        #pragma unroll
        for (int r = 0; r < 4; ++r) {
            const int m = m0 + u * 4 + r;
            const int n = n0 + ni * 16 + fr;
            if (sel == 0) {
                qT[((size_t)(n >> 6) * HW + m) * 64 + (n & 63)] = f2bf(acc[r] + bq[n]);
            } else if (sel == 1) {
                kT[((size_t)(n >> 6) * PPK + m) * 64 + (n & 63)] = f2bf(acc[r] + bk[n]);
            } else {
                vP[((size_t)(m >> 6) * 64 + (m & 63)) * PPK + n] = f2bf(acc[r] + bv[m]);
            }
        }
    }
}

// ---------------------------------------------------------------------------
// Kernel 2: MFMA attention, split-p partials. Block = (16q, slice, head);
// grid (36, 4, 8) = 1152 blocks, 4 waves. Per-slice (m, l, O) partials.
// (unchanged from the R3-verified version)
// ---------------------------------------------------------------------------
__global__ __launch_bounds__(256) void attn3(
    const unsigned short* __restrict__ qT, const unsigned short* __restrict__ kT,
    const unsigned short* __restrict__ vP, float* __restrict__ mP,
    float* __restrict__ lP, unsigned short* __restrict__ Op)
{
    const int q0 = blockIdx.x * 16;
    const int s  = blockIdx.y;
    const int hd = blockIdx.z;
    const int t  = threadIdx.x;
    const int lane = t & 63, w = t >> 6;
    const int fr = lane & 15, u = lane >> 4;

    __shared__ float cnt_s[SP];                   // multiplicity table
    __shared__ __align__(16) unsigned short Wl[16 * 272];  // weights [q][p+pad]
    __shared__ float mw[64], lw[64];

    if (t < SP) {                                 // cnt(y)*cnt(x), 0 for pads
        const int p = s * SP + t;
        float c = 0.f;
        if (p < 900) {
            const int y = p / PW, xw = p - y * PW;
            int cy = y + 1;  if (PW - y  < cy) cy = PW - y;  if (cy > 7) cy = 7;
            int cx = xw + 1; if (PW - xw < cx) cx = PW - xw; if (cx > 7) cx = 7;
            c = (float)(cy * cx);
        }
        cnt_s[t] = c;
    }

    // q B-frags (shared across this wave's p-tiles)
    const unsigned short* qrow = qT + ((size_t)hd * HW + q0 + fr) * 64 + u * 8;
    const s16x8 b0 = *(const s16x8*)qrow;
    const s16x8 b1 = *(const s16x8*)(qrow + 32);

    // QK: 4 E^T tiles (16p x 16q) per wave
    f32x4 e[4];
    #pragma unroll
    for (int t4 = 0; t4 < 4; ++t4) {
        const unsigned short* krow =
            kT + ((size_t)hd * PPK + s * SP + w * 64 + t4 * 16 + fr) * 64 + u * 8;
        const s16x8 a0 = *(const s16x8*)krow;
        const s16x8 a1 = *(const s16x8*)(krow + 32);
        f32x4 a = (f32x4){0.f, 0.f, 0.f, 0.f};
        a = __builtin_amdgcn_mfma_f32_16x16x32_bf16(a0, b0, a, 0, 0, 0);
        a = __builtin_amdgcn_mfma_f32_16x16x32_bf16(a1, b1, a, 0, 0, 0);
        e[t4] = a;
    }

    // per-q max (all regs share q = fr; cross-quad via 2 shuffles)
    float m = -1e30f;
    #pragma unroll
    for (int t4 = 0; t4 < 4; ++t4)
        #pragma unroll
        for (int r = 0; r < 4; ++r) m = fmaxf(m, e[t4][r]);
    m = fmaxf(m, __shfl_xor(m, 16));
    m = fmaxf(m, __shfl_xor(m, 32));
    if (lane < 16) mw[w * 16 + lane] = m;
    __syncthreads();
    const float mq = fmaxf(fmaxf(mw[fr], mw[16 + fr]), fmaxf(mw[32 + fr], mw[48 + fr]));

    // weights = cnt * exp(e - mq): bf16 into Wl; per-q partial sums
    float sum = 0.f;
    #pragma unroll
    for (int t4 = 0; t4 < 4; ++t4) {
        unsigned short wb4[4];
        #pragma unroll
        for (int r = 0; r < 4; ++r) {
            const float wv2 = cnt_s[w * 64 + t4 * 16 + u * 4 + r] *
                              __expf(e[t4][r] - mq);
            sum += wv2;
            wb4[r] = f2bf(wv2);
        }
        const int ho = fr * 272 + w * 64 + t4 * 16 + u * 4;
        *(unsigned*)&Wl[ho]     = (unsigned)wb4[0] | ((unsigned)wb4[1] << 16);
        *(unsigned*)&Wl[ho + 2] = (unsigned)wb4[2] | ((unsigned)wb4[3] << 16);
    }
    sum += __shfl_xor(sum, 16);
    sum += __shfl_xor(sum, 32);
    if (lane < 16) lw[w * 16 + lane] = sum;
    __syncthreads();

    if (t < 16) {                                 // store per-slice stats
        const float lq = lw[t] + lw[16 + t] + lw[32 + t] + lw[48 + t];
        const float mq2 = fmaxf(fmaxf(mw[t], mw[16 + t]),
                                fmaxf(mw[32 + t], mw[48 + t]));
        const int si = (hd * NS + s) * HW + q0 + t;
        lP[si] = lq;
        mP[si] = mq2;
    }

    // PV: wave w owns d-tile w; O[16q][16d] over this slice's 256 p
    f32x4 o = (f32x4){0.f, 0.f, 0.f, 0.f};
    const unsigned short* vrow =
        vP + ((size_t)hd * 64 + w * 16 + fr) * PPK + s * SP + u * 8;
    #pragma unroll
    for (int c = 0; c < 8; ++c) {
        const s16x8 aw = *(const s16x8*)&Wl[fr * 272 + c * 32 + u * 8];
        const s16x8 bv2 = *(const s16x8*)(vrow + c * 32);
        o = __builtin_amdgcn_mfma_f32_16x16x32_bf16(aw, bv2, o, 0, 0, 0);
    }
    #pragma unroll
    for (int r = 0; r < 4; ++r) {                 // C layout: row=q, col=d
        const size_t oi =
            ((size_t)(hd * NS + s) * HW + q0 + u * 4 + r) * 64 + w * 16 + fr;
        Op[oi] = f2bf(o[r]);
    }
}

// ---------------------------------------------------------------------------
// Kernel 3: merge the 4 p-slice partials; out = gamma * O/l + x.
// Block = (64q-tile, head); Op reads fully coalesced (thread = (q, 16d)).
// ---------------------------------------------------------------------------
__global__ __launch_bounds__(256) void combine2(
    const unsigned short* __restrict__ Op, const float* __restrict__ mP,
    const float* __restrict__ lP, const float* __restrict__ x,
    const float* __restrict__ gamma, float* __restrict__ out)
{
    const int hd = blockIdx.y;
    const int q  = blockIdx.x * 64 + (threadIdx.x >> 2);
    const int dq = (threadIdx.x & 3) * 16;

    const int sb = (hd * NS) * HW + q;
    const float m0 = mP[sb], m1 = mP[sb + HW];
    const float m2 = mP[sb + 2 * HW], m3 = mP[sb + 3 * HW];
    const float ms = fmaxf(fmaxf(m0, m1), fmaxf(m2, m3));
    const float a[NS] = {__expf(m0 - ms), __expf(m1 - ms),
                         __expf(m2 - ms), __expf(m3 - ms)};
    const float l = lP[sb] * a[0] + lP[sb + HW] * a[1] +
                    lP[sb + 2 * HW] * a[2] + lP[sb + 3 * HW] * a[3];
    const float scale = gamma[0] / l;

    float o[16] = {};
    #pragma unroll
    for (int s = 0; s < NS; ++s) {
        const unsigned short* op = &Op[((size_t)(sb + s * HW)) * 64 + dq];
        const uint4 u0 = *(const uint4*)op;
        const uint4 u1 = *(const uint4*)(op + 8);
        const unsigned uu[8] = {u0.x, u0.y, u0.z, u0.w, u1.x, u1.y, u1.z, u1.w};
        #pragma unroll
        for (int j = 0; j < 8; ++j) {
            o[2 * j]     = fmaf(a[s], bf2f((unsigned short)(uu[j] & 0xFFFF)), o[2 * j]);
            o[2 * j + 1] = fmaf(a[s], bf2f((unsigned short)(uu[j] >> 16)),    o[2 * j + 1]);
        }
    }
    #pragma unroll
    for (int i = 0; i < 16; ++i) {
        const size_t gi = (size_t)(hd * 64 + dq + i) * HW + q;
        out[gi] = fmaf(scale, o[i], x[gi]);
    }
}

// ---------------------------------------------------------------------------
extern "C" void kernel_launch(void* const* d_in, const int* in_sizes, int n_in,
                              void* d_out, int out_size, void* d_ws, size_t ws_size,
                              hipStream_t stream) {
    const float* x     = (const float*)d_in[0];
    const float* Wq    = (const float*)d_in[1];
    const float* bq    = (const float*)d_in[2];
    const float* Wk    = (const float*)d_in[3];
    const float* bk    = (const float*)d_in[4];
    const float* Wv    = (const float*)d_in[5];
    const float* bv    = (const float*)d_in[6];
    const float* gamma = (const float*)d_in[7];
    float* out = (float*)d_out;

    char* wsb = (char*)d_ws;
    unsigned short* qT = (unsigned short*)(wsb + OFF_QT);
    unsigned short* kT = (unsigned short*)(wsb + OFF_KT);
    unsigned short* vP = (unsigned short*)(wsb + OFF_VP);
    float*          mP = (float*)(wsb + OFF_MP);
    float*          lP = (float*)(wsb + OFF_LP);
    unsigned short* Op = (unsigned short*)(wsb + OFF_OP);
    unsigned short* xT = (unsigned short*)(wsb + OFF_XT);
    unsigned short* wb = (unsigned short*)(wsb + OFF_WB);

    cvtT<<<dim3(457), 256, 0, stream>>>(x, Wq, Wk, Wv, xT, wb);
    qkv_direct<<<dim3(656), 256, 0, stream>>>(xT, wb, bq, bk, bv, qT, kT, vP);
    attn3<<<dim3(36, NS, 8), 256, 0, stream>>>(qT, kT, vP, mP, lP, Op);
    combine2<<<dim3(9, 8), 256, 0, stream>>>(Op, mP, lP, x, gamma, out);
}